// Round 1
// baseline (285.827 us; speedup 1.0000x reference)
//
#include <hip/hip_runtime.h>
#include <hip/hip_bf16.h>
#include <stdint.h>

// Shapes (fixed by the problem)
#define S_LEN  2048
#define DMODEL 1024
#define NHEADS 16
#define DKH    64
#define KDIM   1024

typedef __bf16 bf16x8 __attribute__((ext_vector_type(8)));
typedef __bf16 bf16x2 __attribute__((ext_vector_type(2)));
typedef float  floatx4 __attribute__((ext_vector_type(4)));
typedef float  floatx16 __attribute__((ext_vector_type(16)));
typedef unsigned short ushort8v __attribute__((ext_vector_type(8)));
typedef unsigned int  uint32x2 __attribute__((ext_vector_type(2)));
typedef unsigned int  uint32x4 __attribute__((ext_vector_type(4)));

// async global->LDS, 16B per lane; LDS dest = wave-uniform base + lane*16
__device__ inline void gll16(const __bf16* g, const __bf16* l) {
    __builtin_amdgcn_global_load_lds(
        (const __attribute__((address_space(1))) void*)g,
        (__attribute__((address_space(3))) void*)l, 16, 0, 0);
}

__device__ inline float fast_exp2(float x) {
#if __has_builtin(__builtin_amdgcn_exp2f)
    return __builtin_amdgcn_exp2f(x);
#else
    return exp2f(x);
#endif
}

// sign-extended 1-bit field extract: returns 0 or -1 (v_bfe_i32, 1 inst)
__device__ inline int bit_sign(uint32_t v, int idx) {
#if __has_builtin(__builtin_amdgcn_sbfe)
    return __builtin_amdgcn_sbfe((int)v, (uint32_t)idx, 1u);
#else
    return ((int)(v << (31 - idx))) >> 31;
#endif
}

// v_permlane32_swap_b32: row1 (lanes 32-63) of a  <->  row0 (lanes 0-31) of b
__device__ inline void plswap(uint32_t& a, uint32_t& b) {
    asm volatile("v_permlane32_swap_b32 %0, %1" : "+v"(a), "+v"(b));
}

// ---------------------------------------------------------------------------
// Fused prep: blocks [0,8192) convert fp32 inputs (q,k,v,wq,wk,wv,wo =
// 2^24 elems) to bf16; blocks [8192,24576) bit-pack the mask via ballot.
// ---------------------------------------------------------------------------
__global__ __launch_bounds__(256) void prep_kernel(
    const float* __restrict__ q, const float* __restrict__ k, const float* __restrict__ v,
    const float* __restrict__ wq, const float* __restrict__ wk, const float* __restrict__ wv,
    const float* __restrict__ wo, __bf16* __restrict__ out,
    const int* __restrict__ M, uint64_t* __restrict__ P) {
    if (blockIdx.x < 8192) {
        const size_t i8 = ((size_t)blockIdx.x * 256 + threadIdx.x) * 8;
        const float* src;
        if (i8 < 4194304u)        src = q  + i8;
        else if (i8 < 8388608u)   src = k  + (i8 - 4194304u);
        else if (i8 < 12582912u)  src = v  + (i8 - 8388608u);
        else if (i8 < 13631488u)  src = wq + (i8 - 12582912u);
        else if (i8 < 14680064u)  src = wk + (i8 - 13631488u);
        else if (i8 < 15728640u)  src = wv + (i8 - 14680064u);
        else                      src = wo + (i8 - 15728640u);
        floatx4 a = *(const floatx4*)src;
        floatx4 b = *(const floatx4*)(src + 4);
        bf16x8 r;
#pragma unroll
        for (int i = 0; i < 4; ++i) { r[i] = (__bf16)a[i]; r[i + 4] = (__bf16)b[i]; }
        *(bf16x8*)(out + i8) = r;
    } else {
        const size_t i = ((size_t)(blockIdx.x - 8192)) * 256 + threadIdx.x;
        uint64_t bits = __ballot(M[i] != 0);
        if ((threadIdx.x & 63) == 0) P[i >> 6] = bits;
    }
}

// ---------------------------------------------------------------------------
// Fused QKV projection (unchanged from R8): 128x64 tiles, 512 blocks/job.
// ---------------------------------------------------------------------------
__global__ __launch_bounds__(256, 5) void qkv_gemm(
    const __bf16* __restrict__ qb, const __bf16* __restrict__ kb, const __bf16* __restrict__ vb,
    const __bf16* __restrict__ wqw, const __bf16* __restrict__ wkw, const __bf16* __restrict__ wvw,
    const float* __restrict__ biasq, const float* __restrict__ biask, const float* __restrict__ biasv,
    __bf16* __restrict__ qh, __bf16* __restrict__ kh, __bf16* __restrict__ vt) {
    __shared__ __align__(16) __bf16 As[2 * 128 * 32];
    __shared__ __align__(16) __bf16 Bs[2 * 64 * 32];

    const int lane = threadIdx.x & 63;
    const int wave = threadIdx.x >> 6;
    const int quad = lane >> 4;
    const int l15  = lane & 15;

    const int bid = blockIdx.x;
    const int job = bid >> 9;
    const int tt  = bid & 511;
    const __bf16* A; const __bf16* Bm; const float* bias; __bf16* C;
    int bx, by, MODE;
    if (job == 0)      { A = qb;  Bm = wqw; bias = biasq; C = qh; bx = tt & 15; by = tt >> 4; MODE = 0; }
    else if (job == 1) { A = kb;  Bm = wkw; bias = biask; C = kh; bx = tt & 15; by = tt >> 4; MODE = 0; }
    else               { A = wvw; Bm = vb;  bias = biasv; C = vt; bx = tt & 63; by = tt >> 6; MODE = 1; }

    const int m_t = by * 128, n_t = bx * 64;
    const int m0w = (wave >> 1) * 64, n0w = (wave & 1) * 32;

    const int lrow = lane >> 2;
    const int scol = ((lane & 3) ^ (lrow & 3)) * 8;

    floatx4 acc[4][2];
#pragma unroll
    for (int i = 0; i < 4; ++i)
#pragma unroll
        for (int j = 0; j < 2; ++j)
            acc[i][j] = (floatx4){0.f, 0.f, 0.f, 0.f};

    for (int kk = 0; kk < KDIM; kk += 64) {
#pragma unroll
        for (int u = 0; u < 6; ++u) {
            const int pi = wave * 6 + u;          // 24 portions of 1 KB
            if (pi < 16) {                        // A: 2 panels x 8 rowblocks
                const int panel = pi >> 3, rb = pi & 7;
                gll16(A + (size_t)(m_t + rb * 16 + lrow) * KDIM + kk + panel * 32 + scol,
                      As + (panel * 128 + rb * 16) * 32);
            } else {                              // B: 2 panels x 4 rowblocks
                const int qi = pi - 16, panel = qi >> 2, rb = qi & 3;
                gll16(Bm + (size_t)(n_t + rb * 16 + lrow) * KDIM + kk + panel * 32 + scol,
                      Bs + (panel * 64 + rb * 16) * 32);
            }
        }
        __syncthreads();
        const int cq = (quad ^ (l15 & 3)) * 8;
#pragma unroll
        for (int p = 0; p < 2; ++p) {
            bf16x8 af[4], bfr[2];
#pragma unroll
            for (int i = 0; i < 4; ++i)
                af[i] = *(const bf16x8*)(As + (p * 128 + m0w + i * 16 + l15) * 32 + cq);
#pragma unroll
            for (int j = 0; j < 2; ++j)
                bfr[j] = *(const bf16x8*)(Bs + (p * 64 + n0w + j * 16 + l15) * 32 + cq);
#pragma unroll
            for (int i = 0; i < 4; ++i)
#pragma unroll
                for (int j = 0; j < 2; ++j)
                    acc[i][j] = __builtin_amdgcn_mfma_f32_16x16x32_bf16(af[i], bfr[j], acc[i][j], 0, 0, 0);
        }
        __syncthreads();
    }

#pragma unroll
    for (int j = 0; j < 2; ++j) {
        const int n = n_t + n0w + j * 16 + l15;
        float bn = (MODE == 1) ? 0.f : bias[n];
#pragma unroll
        for (int i = 0; i < 4; ++i) {
#pragma unroll
            for (int r = 0; r < 4; ++r) {
                const int m = m_t + m0w + i * 16 + quad * 4 + r;
                float bv = (MODE == 1) ? bias[m] : bn;
                float v = acc[i][j][r] + bv;
                size_t off;
                if (MODE == 0) {
                    off = ((size_t)((m >> 11) * 16 + (n >> 6)) * 2048 + (m & 2047)) * 64 + (n & 63);
                } else {
                    off = ((size_t)((n >> 11) * 16 + (m >> 6)) * 64 + (m & 63)) * 2048 + (n & 2047);
                }
                C[off] = (__bf16)v;
            }
        }
    }
}

// ---------------------------------------------------------------------------
// Output GEMM (unchanged): 128x64 tiles, 512 blocks.
// ---------------------------------------------------------------------------
__global__ __launch_bounds__(256) void gemm_out(const __bf16* __restrict__ A,
                                                const __bf16* __restrict__ Bm,
                                                const float* __restrict__ bias,
                                                float* __restrict__ C) {
    __shared__ __align__(16) __bf16 As[2 * 128 * 32];
    __shared__ __align__(16) __bf16 Bs[2 * 64 * 32];

    const int lane = threadIdx.x & 63;
    const int wave = threadIdx.x >> 6;
    const int quad = lane >> 4;
    const int l15  = lane & 15;
    const int m_t = blockIdx.y * 128, n_t = blockIdx.x * 64;
    const int m0w = (wave >> 1) * 64, n0w = (wave & 1) * 32;

    const int lrow = lane >> 2;
    const int scol = ((lane & 3) ^ (lrow & 3)) * 8;

    floatx4 acc[4][2];
#pragma unroll
    for (int i = 0; i < 4; ++i)
#pragma unroll
        for (int j = 0; j < 2; ++j)
            acc[i][j] = (floatx4){0.f, 0.f, 0.f, 0.f};

    for (int kk = 0; kk < KDIM; kk += 64) {
#pragma unroll
        for (int u = 0; u < 6; ++u) {
            const int pi = wave * 6 + u;          // 24 portions of 1 KB
            if (pi < 16) {
                const int panel = pi >> 3, rb = pi & 7;
                gll16(A + (size_t)(m_t + rb * 16 + lrow) * KDIM + kk + panel * 32 + scol,
                      As + (panel * 128 + rb * 16) * 32);
            } else {
                const int qi = pi - 16, panel = qi >> 2, rb = qi & 3;
                gll16(Bm + (size_t)(n_t + rb * 16 + lrow) * KDIM + kk + panel * 32 + scol,
                      Bs + (panel * 64 + rb * 16) * 32);
            }
        }
        __syncthreads();
        const int cq = (quad ^ (l15 & 3)) * 8;
#pragma unroll
        for (int p = 0; p < 2; ++p) {
            bf16x8 af[4], bfr[2];
#pragma unroll
            for (int i = 0; i < 4; ++i)
                af[i] = *(const bf16x8*)(As + (p * 128 + m0w + i * 16 + l15) * 32 + cq);
#pragma unroll
            for (int j = 0; j < 2; ++j)
                bfr[j] = *(const bf16x8*)(Bs + (p * 64 + n0w + j * 16 + l15) * 32 + cq);
#pragma unroll
            for (int i = 0; i < 4; ++i)
#pragma unroll
                for (int j = 0; j < 2; ++j)
                    acc[i][j] = __builtin_amdgcn_mfma_f32_16x16x32_bf16(af[i], bfr[j], acc[i][j], 0, 0, 0);
        }
        __syncthreads();
    }

#pragma unroll
    for (int j = 0; j < 2; ++j) {
        const int n = n_t + n0w + j * 16 + l15;
        const float bn = bias[n];
#pragma unroll
        for (int i = 0; i < 4; ++i)
#pragma unroll
            for (int r = 0; r < 4; ++r) {
                const int m = m_t + m0w + i * 16 + quad * 4 + r;
                C[(size_t)m * 1024 + n] = acc[i][j][r] + bn;
            }
    }
}

// ---------------------------------------------------------------------------
// Flash attention R9: 32x32x16 MFMA restructure.
// Block = 64 q rows, 4 waves: wave = (qhalf, keyhalf). Each wave computes
// 32 q x 32 keys per tile: QK = 4 mfma_32x32x16 (A=K rows, B=Q), softmax
// in-register (lane owns one q row's 16 scores), P->B-frag relayout via
// cvt_pk + v_permlane32_swap_b32, PV = 4 mfma_32x32x16 (A=V^T), f32 scalar
// denominator. LDS is fragment-ordered (block + lane*16B): all ds_read_b128
// are linear/conflict-free and match global_load_lds's write pattern; the
// fragment permutation lives in the per-lane global staging addresses.
// Key-half partial O reduced across wave pairs through LDS in the epilogue.
// Halves LDS-read traffic per FLOP vs R8 (8 ds_read_b128/wave/tile, was 16).
// ---------------------------------------------------------------------------
__global__ __launch_bounds__(256, 4) void attn_kernel(const __bf16* __restrict__ Qh,
                                                      const __bf16* __restrict__ Kh,
                                                      const __bf16* __restrict__ Vt,
                                                      const uint64_t* __restrict__ PM,
                                                      __bf16* __restrict__ X) {
    __shared__ __align__(16) __bf16 Ks[2][4096];   // [buf][ (kh*4+ks)*64 + lane ]*8
    __shared__ __align__(16) __bf16 Vs[2][4096];   // [buf][ (dt*4+kh*2+c)*64 + lane ]*8

    const int lane = threadIdx.x & 63;
    const int wave = threadIdx.x >> 6;
    const int l31  = lane & 31;
    const int hi   = lane >> 5;
    const int kh   = wave & 1;         // key-half owned by this wave
    const int qhf  = wave >> 1;        // q-half (32 rows)

    // XCD-aware decode: bid&7 ~ XCD id; 4 (b,h) groups per XCD
    const int bid  = blockIdx.x;       // 0..1023
    const int xcd  = bid & 7;
    const int slot = bid >> 3;         // 0..127
    const int grp  = xcd * 4 + (slot >> 5);
    const int qt   = slot & 31;
    const int b = grp >> 4, h = grp & 15;
    const int qw = qt * 64 + qhf * 32; // wave's q base

    const __bf16* Qb = Qh + (size_t)(b * NHEADS + h) * S_LEN * DKH;
    const __bf16* Kb = Kh + (size_t)(b * NHEADS + h) * S_LEN * DKH;
    const __bf16* Vb = Vt + (size_t)(b * NHEADS + h) * DKH * S_LEN;
    const uint64_t* pr = PM + (size_t)(qw + l31) * (S_LEN / 64);

    const float cs = 0.18033688011112042f;  // log2(e)/sqrt(64)

    // Per-lane global staging offsets (elements). Wave stages 2 K-blocks and
    // 2 V-blocks of 1KB each; block pi = wave*2+i.
    //   K block pi: kh_s=pi>>2, ks=pi&3 -> K[key0+kh_s*32+l31][ks*16+hi*8 ..]
    //   V block pi: dt=pi>>2, khv=(pi>>1)&1, c=pi&1
    //              -> V^T[dt*32+l31][key0+khv*32+c*16+hi*8 ..]
    uint32_t offK[2], offV[2];
#pragma unroll
    for (int i = 0; i < 2; ++i) {
        const int pi  = wave * 2 + i;
        const int khs = pi >> 2, kss = pi & 3;
        offK[i] = (uint32_t)((khs * 32 + l31) * DKH + kss * 16 + hi * 8);
        const int dts = pi >> 2, khv = (pi >> 1) & 1, cv = pi & 1;
        offV[i] = (uint32_t)((dts * 32 + l31) * S_LEN + khv * 32 + cv * 16 + hi * 8);
    }

    auto stage = [&](int p, int key0) {
#pragma unroll
        for (int i = 0; i < 2; ++i) {
            gll16(Kb + (size_t)key0 * DKH + offK[i], Ks[p] + (wave * 2 + i) * 512);
            gll16(Vb + (size_t)key0 + offV[i],       Vs[p] + (wave * 2 + i) * 512);
        }
    };

    // Q fragments (B operand, col=q=l31, k = ks*16 + hi*8 + j), held all loop
    bf16x8 qf[4];
#pragma unroll
    for (int ks = 0; ks < 4; ++ks)
        qf[ks] = *(const bf16x8*)(Qb + (size_t)(qw + l31) * DKH + ks * 16 + hi * 8);

    floatx16 o0, o1;                   // PV accum: dt=0 (d 0..31), dt=1 (d 32..63)
#pragma unroll
    for (int i = 0; i < 16; ++i) { o0[i] = 0.f; o1[i] = 0.f; }
    float ls0 = 0.f;                   // denominator partial (this lane's keys)

    const __bf16* Kl = &Ks[0][kh * 2048 + lane * 8];
    const __bf16* Vl = &Vs[0][kh * 1024 + lane * 8];

    stage(0, 0);
    uint64_t mwc = pr[0];              // prefetched mask word (64 keys/tile)

    for (int kt = 0; kt < 32; ++kt) {
        const int p = kt & 1;
        __syncthreads();               // buf[p] staged; buf[p^1] reads done
        if (kt < 31) stage(p ^ 1, (kt + 1) * 64);
        const uint64_t mw = mwc;
        if (kt < 31) mwc = pr[kt + 1];

        const __bf16* Kp = Kl + p * 4096;
        const __bf16* Vp = Vl + p * 4096;

        // QK: D[key][q] for this wave's 32 keys x 32 q, K-accum over d=64
        floatx16 st;
#pragma unroll
        for (int i = 0; i < 16; ++i) st[i] = 0.f;
#pragma unroll
        for (int ks = 0; ks < 4; ++ks) {
            bf16x8 kf = *(const bf16x8*)(Kp + ks * 512);
            st = __builtin_amdgcn_mfma_f32_32x32x16_bf16(kf, qf[ks], st, 0, 0, 0);
        }

        // Mask: lane's q row word; key bit = kh*32 + (r&3)+8*(r>>2)+4*hi
        const uint32_t w32 = (uint32_t)(kh ? (mw >> 32) : mw);
        const uint32_t wsh = w32 >> (hi * 4);

        // Softmax (no max subtraction; cs*score <= ~9 fits bf16 easily)
        float e[16];
#pragma unroll
        for (int r = 0; r < 16; ++r) {
            const int cpos = (r & 3) + 8 * (r >> 2);
            float v = fast_exp2(st[r] * cs);
            const int sgn = bit_sign(wsh, cpos);   // 0 or -1
            e[r] = __builtin_bit_cast(float, __builtin_bit_cast(int, v) & sgn);
        }
        ls0 += (((e[0] + e[1]) + (e[2] + e[3])) + ((e[4] + e[5]) + (e[6] + e[7])))
             + (((e[8] + e[9]) + (e[10] + e[11])) + ((e[12] + e[13]) + (e[14] + e[15])));

        // Pack to bf16 pairs, then half-swap to build PV B-frags
        uint32_t w[8];
#pragma unroll
        for (int r2 = 0; r2 < 8; ++r2) {
            bf16x2 pp; pp[0] = (__bf16)e[2 * r2]; pp[1] = (__bf16)e[2 * r2 + 1];
            w[r2] = __builtin_bit_cast(uint32_t, pp);
        }
        plswap(w[0], w[2]);   // -> frag0 word0, word2
        plswap(w[1], w[3]);   // -> frag0 word1, word3
        plswap(w[4], w[6]);   // -> frag1 word0, word2
        plswap(w[5], w[7]);   // -> frag1 word1, word3
        uint32x4 f0 = {w[0], w[1], w[2], w[3]};
        uint32x4 f1 = {w[4], w[5], w[6], w[7]};
        bf16x8 pf0 = __builtin_bit_cast(bf16x8, f0);
        bf16x8 pf1 = __builtin_bit_cast(bf16x8, f1);

        // PV: O[d][q] += V^T frags x P frags (keys of this wave's half)
        bf16x8 vf;
        vf = *(const bf16x8*)(Vp + 0 * 2048 + 0 * 512);
        o0 = __builtin_amdgcn_mfma_f32_32x32x16_bf16(vf, pf0, o0, 0, 0, 0);
        vf = *(const bf16x8*)(Vp + 0 * 2048 + 1 * 512);
        o0 = __builtin_amdgcn_mfma_f32_32x32x16_bf16(vf, pf1, o0, 0, 0, 0);
        vf = *(const bf16x8*)(Vp + 1 * 2048 + 0 * 512);
        o1 = __builtin_amdgcn_mfma_f32_32x32x16_bf16(vf, pf0, o1, 0, 0, 0);
        vf = *(const bf16x8*)(Vp + 1 * 2048 + 1 * 512);
        o1 = __builtin_amdgcn_mfma_f32_32x32x16_bf16(vf, pf1, o1, 0, 0, 0);
    }

    // lane holds half-pattern key sums; combine across hi (same q at l^32)
    float lsum2 = ls0 + __shfl_xor(ls0, 32);

    // Key-half reduction through LDS (overlay on K/V buffers)
    __syncthreads();
    float* red  = (float*)&Ks[0][0];   // 4096 floats = 16 KB, rows [64][64]
    float* redl = (float*)&Vs[0][0];   // 128 floats
    if (kh == 1) {
#pragma unroll
        for (int g = 0; g < 16; ++g) red[(qhf * 32 + g) * 64 + lane] = o0[g];
#pragma unroll
        for (int g = 0; g < 16; ++g) red[(qhf * 32 + 16 + g) * 64 + lane] = o1[g];
        redl[qhf * 64 + lane] = lsum2;
    }
    __syncthreads();
    if (kh == 0) {
        const float lt  = lsum2 + redl[qhf * 64 + lane];
        const float inv = (lt > 0.f) ? (1.f / lt) : 0.f;
        unsigned short* xp = (unsigned short*)X +
            (size_t)(b * S_LEN + qw + l31) * DMODEL + h * DKH;
        // dt = 0 (d 0..31): regs r -> d = (r&3) + 8*(r>>2) + 4*hi
#pragma unroll
        for (int g = 0; g < 4; ++g) {
            float va = (o0[g * 4 + 0] + red[(qhf * 32 + g * 4 + 0) * 64 + lane]) * inv;
            float vb = (o0[g * 4 + 1] + red[(qhf * 32 + g * 4 + 1) * 64 + lane]) * inv;
            float vc = (o0[g * 4 + 2] + red[(qhf * 32 + g * 4 + 2) * 64 + lane]) * inv;
            float vd = (o0[g * 4 + 3] + red[(qhf * 32 + g * 4 + 3) * 64 + lane]) * inv;
            bf16x2 pa; pa[0] = (__bf16)va; pa[1] = (__bf16)vb;
            bf16x2 pb; pb[0] = (__bf16)vc; pb[1] = (__bf16)vd;
            uint32x2 wv = {__builtin_bit_cast(uint32_t, pa), __builtin_bit_cast(uint32_t, pb)};
            *(uint32x2*)(xp + g * 8 + hi * 4) = wv;
        }
        // dt = 1 (d 32..63)
#pragma unroll
        for (int g = 0; g < 4; ++g) {
            float va = (o1[g * 4 + 0] + red[(qhf * 32 + 16 + g * 4 + 0) * 64 + lane]) * inv;
            float vb = (o1[g * 4 + 1] + red[(qhf * 32 + 16 + g * 4 + 1) * 64 + lane]) * inv;
            float vc = (o1[g * 4 + 2] + red[(qhf * 32 + 16 + g * 4 + 2) * 64 + lane]) * inv;
            float vd = (o1[g * 4 + 3] + red[(qhf * 32 + 16 + g * 4 + 3) * 64 + lane]) * inv;
            bf16x2 pa; pa[0] = (__bf16)va; pa[1] = (__bf16)vb;
            bf16x2 pb; pb[0] = (__bf16)vc; pb[1] = (__bf16)vd;
            uint32x2 wv = {__builtin_bit_cast(uint32_t, pa), __builtin_bit_cast(uint32_t, pb)};
            *(uint32x2*)(xp + 32 + g * 8 + hi * 4) = wv;
        }
    }
}

// ---------------------------------------------------------------------------
extern "C" void kernel_launch(void* const* d_in, const int* in_sizes, int n_in,
                              void* d_out, int out_size, void* d_ws, size_t ws_size,
                              hipStream_t stream) {
    const float* q   = (const float*)d_in[0];
    const float* k   = (const float*)d_in[1];
    const float* v   = (const float*)d_in[2];
    const int*   msk = (const int*)d_in[3];
    const float* wq  = (const float*)d_in[4];
    const float* wqb = (const float*)d_in[5];
    const float* wk  = (const float*)d_in[6];
    const float* wkb = (const float*)d_in[7];
    const float* wv  = (const float*)d_in[8];
    const float* wvb = (const float*)d_in[9];
    const float* wo  = (const float*)d_in[10];
    const float* wob = (const float*)d_in[11];

    char* ws = (char*)d_ws;
    __bf16*   qh   = (__bf16*)(ws);
    __bf16*   kh   = (__bf16*)(ws + 8388608);
    __bf16*   vt   = (__bf16*)(ws + 16777216);
    uint64_t* pm   = (uint64_t*)(ws + 25165824);            // 524288 B
    __bf16*   cb   = (__bf16*)(ws + 25690112);              // conv region base
    __bf16*   qb   = cb;
    __bf16*   kb   = cb + 4194304;
    __bf16*   vb   = cb + 8388608;
    __bf16*   wqbf = cb + 12582912;
    __bf16*   wkbf = cb + 13631488;
    __bf16*   wvbf = cb + 14680064;
    __bf16*   wobf = cb + 15728640;
    __bf16*   xa   = qb;                                    // alias (qb dead after qkv_gemm)

    prep_kernel<<<24576, 256, 0, stream>>>(q, k, v, wq, wk, wv, wo, cb, msk, pm);
    qkv_gemm<<<1536, 256, 0, stream>>>(qb, kb, vb, wqbf, wkbf, wvbf, wqb, wkb, wvb, qh, kh, vt);
    attn_kernel<<<1024, 256, 0, stream>>>(qh, kh, vt, pm, xa);
    gemm_out<<<dim3(16, 32), 256, 0, stream>>>(xa, wobf, wob, (float*)d_out);
}